// Round 6
// baseline (207.179 us; speedup 1.0000x reference)
//
#include <hip/hip_runtime.h>

#define BLK   256
#define NSAMP 4
#define REG   1480          // dwords per sample LDS region
// per-sample region map (dword offsets):
//  IMG:  halfwords [0..783] = dwords [0..391] (bf16 packed; dead after conv1)
//  P2:   dw [0..149]   (5x5x6 fp32, c*25+pos)   -- aliases dead IMG
//  P3:   dw [152..178] (3x3x3 fp32, c*9+pos)    -- aliases dead IMG
//  W:    dw [392..1203] (811 hypernet weights, fp32)
//  P1:   halfwords [2408..2953] (3ch * 13rows * stride14, bf16 packed)
#define OFF_P2   0
#define OFF_P3   152
#define OFF_W    392
#define HW_P1    2408       // halfword offset of P1 within region

// weight sub-offsets within OFF_W (SPLITS):
//  w1 0..27 (co*9+pp), b1 27..30, w2 30..192 (co*27+pp*3+ci), b2 192..198,
//  w3 198..360 (co*54+pp*6+ci), b3 360..363, w4 363..795 (co*27+pp*3+ci), b4 795..811

__device__ __forceinline__ float bf2f(unsigned short u) {
    return __uint_as_float(((unsigned int)u) << 16);
}
__device__ __forceinline__ unsigned short f2bf(float f) {
    unsigned int x = __float_as_uint(f);
    return (unsigned short)((x + 0x7fffu + ((x >> 16) & 1u)) >> 16);   // RNE
}
// wave-internal LDS ordering fence (DS retire + compiler barrier)
__device__ __forceinline__ void wsync() {
    __builtin_amdgcn_wave_barrier();
    __asm__ volatile("s_waitcnt lgkmcnt(0)" ::: "memory");
    __builtin_amdgcn_wave_barrier();
}

// Runtime dtype detection (proven R2/R4/R5): probe EVEN halfwords.
__device__ __forceinline__ bool is_bf16(const void* p, int elems) {
    const unsigned short* h = (const unsigned short*)p;
    int n = elems; if (n > 32) n = 32;
    int nz = 0, ok = 0;
    for (int i = 0; i < n; i += 2) {
        unsigned short u = h[i];
        if (u == 0) continue;
        ++nz;
        unsigned int e = (u >> 7) & 255u;
        if (e >= 100u && e <= 141u) ++ok;
    }
    if (nz < 4) return true;
    return 4 * ok >= 3 * nz;
}

__global__ __launch_bounds__(BLK, 6)
void dyncnn4_kernel(const void* __restrict__ image,   // [784, B]
                    const void* __restrict__ state,   // [B, 16]
                    const void* __restrict__ W1, const void* __restrict__ b1,
                    const void* __restrict__ W2, const void* __restrict__ b2,
                    const void* __restrict__ W3, const void* __restrict__ b3,
                    void* __restrict__ out,           // [B,16]
                    int B, int nswz)
{
    __shared__ float SH[NSAMP * REG];     // 23680 B
    __shared__ float s_st[NSAMP][16];
    __shared__ float s_h1[NSAMP][16];
    __shared__ float s_h2[NSAMP][16];

    const int t    = threadIdx.x;
    const int wv   = t >> 6;
    const int lane = t & 63;

    const bool im_bf = is_bf16(image, 784 * B);
    const bool st_bf = is_bf16(state, 16 * B);
    const bool w1_bf = is_bf16(W1, 256);
    const bool b1_bf = is_bf16(b1, 16);
    const bool w2_bf = is_bf16(W2, 256);
    const bool b2_bf = is_bf16(b2, 16);
    const bool w3_bf = is_bf16(W3, 12976);
    const bool b3_bf = is_bf16(b3, 811);
    const bool out_bf = im_bf && st_bf && w1_bf && w2_bf && w3_bf;

    int p = blockIdx.x;
    int l = (nswz > 0) ? ((p & 7) * nswz + (p >> 3)) : p;
    const int b0 = l * NSAMP;

    unsigned short* su = (unsigned short*)SH;   // halfword view

    // ==== phase 0: wave0 = MLP, waves1-3 = image staging (no block barrier) ====
    if (wv == 0) {
        int s = lane >> 4, j = lane & 15;
        int gi = (b0 + s) * 16 + j;
        s_st[s][j] = st_bf ? bf2f(((const unsigned short*)state)[gi])
                           : ((const float*)state)[gi];
        wsync();
        float acc = b1_bf ? bf2f(((const unsigned short*)b1)[j])
                          : ((const float*)b1)[j];
#pragma unroll
        for (int k = 0; k < 16; ++k) {
            float w = w1_bf ? bf2f(((const unsigned short*)W1)[k * 16 + j])
                            : ((const float*)W1)[k * 16 + j];
            acc += s_st[s][k] * w;
        }
        s_h1[s][j] = fmaxf(acc, 0.f);
        wsync();
        acc = b2_bf ? bf2f(((const unsigned short*)b2)[j])
                    : ((const float*)b2)[j];
#pragma unroll
        for (int k = 0; k < 16; ++k) {
            float w = w2_bf ? bf2f(((const unsigned short*)W2)[k * 16 + j])
                            : ((const float*)W2)[k * 16 + j];
            acc += s_h1[s][k] * w;
        }
        s_h2[s][j] = fmaxf(acc, 0.f);
    } else {
        if (im_bf) {
            const unsigned short* im = (const unsigned short*)image;
            for (int pix = t - 64; pix < 784; pix += 192) {
                const uint2 v = *(const uint2*)(im + pix * B + b0);
                su[0 * 2 * REG + pix] = (unsigned short)(v.x);
                su[1 * 2 * REG + pix] = (unsigned short)(v.x >> 16);
                su[2 * 2 * REG + pix] = (unsigned short)(v.y);
                su[3 * 2 * REG + pix] = (unsigned short)(v.y >> 16);
            }
        } else {
            const float* im = (const float*)image;
            for (int pix = t - 64; pix < 784; pix += 192) {
                const float4 v = *(const float4*)(im + pix * B + b0);
                su[0 * 2 * REG + pix] = f2bf(v.x);
                su[1 * 2 * REG + pix] = f2bf(v.y);
                su[2 * 2 * REG + pix] = f2bf(v.z);
                su[3 * 2 * REG + pix] = f2bf(v.w);
            }
        }
    }
    __syncthreads();   // barrier #1: image staged + h2 ready

    // ==== head: w = h2 @ W3 + b3, all 4 samples in one W3 pass ====
    {
        float h2r[4][16];
        const float4* hp = (const float4*)&s_h2[0][0];
#pragma unroll
        for (int i = 0; i < 16; ++i) {
            float4 v = hp[i];
            h2r[i >> 2][(i & 3) * 4 + 0] = v.x;
            h2r[i >> 2][(i & 3) * 4 + 1] = v.y;
            h2r[i >> 2][(i & 3) * 4 + 2] = v.z;
            h2r[i >> 2][(i & 3) * 4 + 3] = v.w;
        }
        for (int j = t; j < 811; j += BLK) {
            float bb = b3_bf ? bf2f(((const unsigned short*)b3)[j])
                             : ((const float*)b3)[j];
            float a0 = bb, a1 = bb, a2 = bb, a3 = bb;
            if (w3_bf) {
                const unsigned short* q = (const unsigned short*)W3 + j;
#pragma unroll
                for (int k = 0; k < 16; ++k) {
                    float w = bf2f(q[k * 811]);
                    a0 += h2r[0][k] * w; a1 += h2r[1][k] * w;
                    a2 += h2r[2][k] * w; a3 += h2r[3][k] * w;
                }
            } else {
                const float* q = (const float*)W3 + j;
#pragma unroll
                for (int k = 0; k < 16; ++k) {
                    float w = q[k * 811];
                    a0 += h2r[0][k] * w; a1 += h2r[1][k] * w;
                    a2 += h2r[2][k] * w; a3 += h2r[3][k] * w;
                }
            }
            SH[0 * REG + OFF_W + j] = a0;
            SH[1 * REG + OFF_W + j] = a1;
            SH[2 * REG + OFF_W + j] = a2;
            SH[3 * REG + OFF_W + j] = a3;
        }
    }
    __syncthreads();   // barrier #2: weights ready — conv phase is wave-local

    // ==== per-wave CNN: wave wv owns sample b0+wv ====
    const int sb = wv * REG;

    // ---- conv1 (1->3, 28x28 -> fused pool -> 13x13x3 bf16) ----
    {
        float wc[27], cb[3];
#pragma unroll
        for (int i = 0; i < 27; ++i) wc[i] = SH[sb + OFF_W + i];
#pragma unroll
        for (int c = 0; c < 3; ++c) cb[c] = SH[sb + OFF_W + 27 + c];
        const unsigned* suw = (const unsigned*)&SH[sb];  // 2 pixels per dword
#pragma unroll
        for (int it = 0; it < 3; ++it) {
            int pix = lane + it * 64;
            if (pix < 169) {
                int py = pix / 13, px = pix - py * 13;
                int iy = 2 * py;
                float pt[4][4];
#pragma unroll
                for (int dy = 0; dy < 4; ++dy) {
                    int r = (iy + dy) * 14 + px;
                    unsigned d0 = suw[r], d1 = suw[r + 1];
                    pt[dy][0] = __uint_as_float(d0 << 16);
                    pt[dy][1] = __uint_as_float(d0 & 0xffff0000u);
                    pt[dy][2] = __uint_as_float(d1 << 16);
                    pt[dy][3] = __uint_as_float(d1 & 0xffff0000u);
                }
                unsigned short* op = &su[sb * 2 + HW_P1 + py * 14 + px];
#pragma unroll
                for (int c = 0; c < 3; ++c) {
                    float a00 = 0.f, a01 = 0.f, a10 = 0.f, a11 = 0.f;
#pragma unroll
                    for (int ky = 0; ky < 3; ++ky)
#pragma unroll
                        for (int kx = 0; kx < 3; ++kx) {
                            float w = wc[c * 9 + ky * 3 + kx];
                            a00 += pt[ky][kx] * w;
                            a01 += pt[ky][kx + 1] * w;
                            a10 += pt[ky + 1][kx] * w;
                            a11 += pt[ky + 1][kx + 1] * w;
                        }
                    float m = fmaxf(fmaxf(a00, a01), fmaxf(a10, a11));
                    op[c * 182] = f2bf(fmaxf(m + cb[c], 0.f));
                }
            }
        }
    }
    wsync();

    // ---- conv2 (3->6, 13x13 -> fused pool -> 5x5x6 fp32) ----
    {
        int g = lane >> 5, q = lane & 31;
        if (q < 25) {
            int py = q / 5, px = q - py * 5;
            const unsigned* p1w = (const unsigned*)&SH[sb + 1204];  // P1 dwords
            float pt[3][4][4];
#pragma unroll
            for (int ci = 0; ci < 3; ++ci)
#pragma unroll
                for (int dy = 0; dy < 4; ++dy) {
                    int r = ci * 91 + (2 * py + dy) * 7 + px;
                    unsigned d0 = p1w[r], d1 = p1w[r + 1];
                    pt[ci][dy][0] = __uint_as_float(d0 << 16);
                    pt[ci][dy][1] = __uint_as_float(d0 & 0xffff0000u);
                    pt[ci][dy][2] = __uint_as_float(d1 << 16);
                    pt[ci][dy][3] = __uint_as_float(d1 & 0xffff0000u);
                }
#pragma unroll
            for (int it = 0; it < 3; ++it) {
                int c = it * 2 + g;
                float wreg[27];
                const int wo = sb + OFF_W + 30 + c * 27;
#pragma unroll
                for (int i = 0; i < 27; ++i) wreg[i] = SH[wo + i];
                float a00 = 0.f, a01 = 0.f, a10 = 0.f, a11 = 0.f;
#pragma unroll
                for (int ci = 0; ci < 3; ++ci)
#pragma unroll
                    for (int ky = 0; ky < 3; ++ky)
#pragma unroll
                        for (int kx = 0; kx < 3; ++kx) {
                            float w = wreg[(ky * 3 + kx) * 3 + ci];
                            a00 += pt[ci][ky][kx] * w;
                            a01 += pt[ci][ky][kx + 1] * w;
                            a10 += pt[ci][ky + 1][kx] * w;
                            a11 += pt[ci][ky + 1][kx + 1] * w;
                        }
                float m = fmaxf(fmaxf(a00, a01), fmaxf(a10, a11));
                SH[sb + OFF_P2 + c * 25 + q] = fmaxf(m + SH[sb + OFF_W + 192 + c], 0.f);
            }
        }
    }
    wsync();

    // ---- conv3 (6->3, 5x5 -> 3x3) + relu, 54-lane split over ci halves ----
    {
        float acc = 0.f;
        int pq = lane % 27;            // 0..26: c*9 + pos
        int half = lane / 27;          // 0,1 active; lane>=54 idle
        int c = pq / 9, pos = pq - c * 9;
        int py = pos / 3, px = pos - py * 3;
        if (lane < 54) {
            const int wo = sb + OFF_W + 198 + c * 54;
            const int cb3 = half * 3;
#pragma unroll
            for (int ky = 0; ky < 3; ++ky)
#pragma unroll
                for (int kx = 0; kx < 3; ++kx)
#pragma unroll
                    for (int ci = 0; ci < 3; ++ci)
                        acc += SH[sb + OFF_P2 + (cb3 + ci) * 25 + (py + ky) * 5 + px + kx] *
                               SH[wo + (ky * 3 + kx) * 6 + cb3 + ci];
        }
        float other = __shfl(acc, (lane + 27) & 63);
        if (lane < 27)
            SH[sb + OFF_P3 + pq] = fmaxf(acc + other + SH[sb + OFF_W + 360 + c], 0.f);
    }
    wsync();

    // ---- conv4 (3->16) + bias + residual -> out, 32-lane split over pp ----
    // P3 channel-major (ci*9+pp), w4 spatial-major (pp*3+ci).
    {
        float acc = 0.f;
        int os = lane & 15, h = (lane >> 4) & 1;
        if (lane < 32) {
            const int wo = sb + OFF_W + 363 + os * 27;
            int p0 = h ? 4 : 0, p1 = h ? 9 : 4;
            for (int pp = p0; pp < p1; ++pp)
#pragma unroll
                for (int ci = 0; ci < 3; ++ci)
                    acc += SH[sb + OFF_P3 + ci * 9 + pp] * SH[wo + pp * 3 + ci];
        }
        float other = __shfl(acc, (lane + 16) & 63);
        if (lane < 16) {
            float tot = acc + other + SH[sb + OFF_W + 795 + os] + s_st[wv][os];
            int gi = (b0 + wv) * 16 + os;
            if (out_bf) ((unsigned short*)out)[gi] = f2bf(tot);
            else        ((float*)out)[gi] = tot;
        }
    }
}

extern "C" void kernel_launch(void* const* d_in, const int* in_sizes, int n_in,
                              void* d_out, int out_size, void* d_ws, size_t ws_size,
                              hipStream_t stream) {
    (void)d_ws; (void)ws_size; (void)n_in; (void)out_size;
    int B = in_sizes[1] / 16;              // 16384
    int nblocks = B / NSAMP;               // 4096
    int nswz = (nblocks % 8 == 0) ? (nblocks / 8) : 0;

    dyncnn4_kernel<<<nblocks, BLK, 0, stream>>>(
        d_in[0], d_in[1], d_in[2], d_in[3], d_in[4], d_in[5], d_in[6], d_in[7],
        d_out, B, nswz);
}

// Round 7
// 157.908 us; speedup vs baseline: 1.3120x; 1.3120x over previous
//
#include <hip/hip_runtime.h>

#define BLK   256
#define NSAMP 4
#define REG   1480          // dwords per sample LDS region
// per-sample region map (dword offsets):
//  IMG:  halfwords [0..783] = dwords [0..391] (bf16 packed; dead after conv1)
//  P2:   dw [0..149]   (5x5x6 fp32, c*25+pos)   -- aliases dead IMG
//  P3:   dw [152..178] (3x3x3 fp32, c*9+pos)    -- aliases dead IMG
//  W:    dw [392..1203] (811 hypernet weights, fp32)
//  P1:   halfwords [2408..2953] (3ch * 13rows * stride14, bf16 packed)
#define OFF_P2   0
#define OFF_P3   152
#define OFF_W    392
#define HW_P1    2408       // halfword offset of P1 within region

// weight sub-offsets within OFF_W (SPLITS):
//  w1 0..27 (co*9+pp), b1 27..30, w2 30..192 (co*27+pp*3+ci), b2 192..198,
//  w3 198..360 (co*54+pp*6+ci), b3 360..363, w4 363..795 (co*27+pp*3+ci), b4 795..811

__device__ __forceinline__ float bf2f(unsigned short u) {
    return __uint_as_float(((unsigned int)u) << 16);
}
__device__ __forceinline__ unsigned short f2bf(float f) {
    unsigned int x = __float_as_uint(f);
    return (unsigned short)((x + 0x7fffu + ((x >> 16) & 1u)) >> 16);   // RNE
}
// wave-internal LDS ordering fence (DS retire + compiler barrier)
__device__ __forceinline__ void wsync() {
    __builtin_amdgcn_wave_barrier();
    __asm__ volatile("s_waitcnt lgkmcnt(0)" ::: "memory");
    __builtin_amdgcn_wave_barrier();
}

// Runtime dtype detection (proven R2/R4/R5): probe EVEN halfwords.
__device__ __forceinline__ bool is_bf16(const void* p, int elems) {
    const unsigned short* h = (const unsigned short*)p;
    int n = elems; if (n > 32) n = 32;
    int nz = 0, ok = 0;
    for (int i = 0; i < n; i += 2) {
        unsigned short u = h[i];
        if (u == 0) continue;
        ++nz;
        unsigned int e = (u >> 7) & 255u;
        if (e >= 100u && e <= 141u) ++ok;
    }
    if (nz < 4) return true;
    return 4 * ok >= 3 * nz;
}

// NOTE: bound stays at 5 (VGPR cap 102). R6's bound=6 (cap 85) caused 22 KB/block
// scratch spill (WRITE_SIZE 1->90 MB, dur 89->130 us). HW still schedules 6
// blocks/CU when LDS (24.4 KB) is the binding limit and VGPRs stay <= 85.
__global__ __launch_bounds__(BLK, 5)
void dyncnn4_kernel(const void* __restrict__ image,   // [784, B]
                    const void* __restrict__ state,   // [B, 16]
                    const void* __restrict__ W1, const void* __restrict__ b1,
                    const void* __restrict__ W2, const void* __restrict__ b2,
                    const void* __restrict__ W3, const void* __restrict__ b3,
                    void* __restrict__ out,           // [B,16]
                    int B, int nswz)
{
    __shared__ float SH[NSAMP * REG];     // 23680 B
    __shared__ float s_st[NSAMP][16];
    __shared__ float s_h1[NSAMP][16];
    __shared__ float s_h2[NSAMP][16];

    const int t    = threadIdx.x;
    const int wv   = t >> 6;
    const int lane = t & 63;

    const bool im_bf = is_bf16(image, 784 * B);
    const bool st_bf = is_bf16(state, 16 * B);
    const bool w1_bf = is_bf16(W1, 256);
    const bool b1_bf = is_bf16(b1, 16);
    const bool w2_bf = is_bf16(W2, 256);
    const bool b2_bf = is_bf16(b2, 16);
    const bool w3_bf = is_bf16(W3, 12976);
    const bool b3_bf = is_bf16(b3, 811);
    const bool out_bf = im_bf && st_bf && w1_bf && w2_bf && w3_bf;

    int p = blockIdx.x;
    int l = (nswz > 0) ? ((p & 7) * nswz + (p >> 3)) : p;
    const int b0 = l * NSAMP;

    unsigned short* su = (unsigned short*)SH;   // halfword view

    // ==== phase 0: wave0 = MLP, waves1-3 = image staging (no block barrier) ====
    if (wv == 0) {
        int s = lane >> 4, j = lane & 15;
        int gi = (b0 + s) * 16 + j;
        s_st[s][j] = st_bf ? bf2f(((const unsigned short*)state)[gi])
                           : ((const float*)state)[gi];
        wsync();
        float acc = b1_bf ? bf2f(((const unsigned short*)b1)[j])
                          : ((const float*)b1)[j];
#pragma unroll
        for (int k = 0; k < 16; ++k) {
            float w = w1_bf ? bf2f(((const unsigned short*)W1)[k * 16 + j])
                            : ((const float*)W1)[k * 16 + j];
            acc += s_st[s][k] * w;
        }
        s_h1[s][j] = fmaxf(acc, 0.f);
        wsync();
        acc = b2_bf ? bf2f(((const unsigned short*)b2)[j])
                    : ((const float*)b2)[j];
#pragma unroll
        for (int k = 0; k < 16; ++k) {
            float w = w2_bf ? bf2f(((const unsigned short*)W2)[k * 16 + j])
                            : ((const float*)W2)[k * 16 + j];
            acc += s_h1[s][k] * w;
        }
        s_h2[s][j] = fmaxf(acc, 0.f);
    } else {
        if (im_bf) {
            const unsigned short* im = (const unsigned short*)image;
            for (int pix = t - 64; pix < 784; pix += 192) {
                const uint2 v = *(const uint2*)(im + pix * B + b0);
                su[0 * 2 * REG + pix] = (unsigned short)(v.x);
                su[1 * 2 * REG + pix] = (unsigned short)(v.x >> 16);
                su[2 * 2 * REG + pix] = (unsigned short)(v.y);
                su[3 * 2 * REG + pix] = (unsigned short)(v.y >> 16);
            }
        } else {
            const float* im = (const float*)image;
            for (int pix = t - 64; pix < 784; pix += 192) {
                const float4 v = *(const float4*)(im + pix * B + b0);
                su[0 * 2 * REG + pix] = f2bf(v.x);
                su[1 * 2 * REG + pix] = f2bf(v.y);
                su[2 * 2 * REG + pix] = f2bf(v.z);
                su[3 * 2 * REG + pix] = f2bf(v.w);
            }
        }
    }
    __syncthreads();   // barrier #1: image staged + h2 ready

    // ==== head: w = h2 @ W3 + b3, all 4 samples in one W3 pass ====
    {
        float h2r[4][16];
        const float4* hp = (const float4*)&s_h2[0][0];
#pragma unroll
        for (int i = 0; i < 16; ++i) {
            float4 v = hp[i];
            h2r[i >> 2][(i & 3) * 4 + 0] = v.x;
            h2r[i >> 2][(i & 3) * 4 + 1] = v.y;
            h2r[i >> 2][(i & 3) * 4 + 2] = v.z;
            h2r[i >> 2][(i & 3) * 4 + 3] = v.w;
        }
        for (int j = t; j < 811; j += BLK) {
            float bb = b3_bf ? bf2f(((const unsigned short*)b3)[j])
                             : ((const float*)b3)[j];
            float a0 = bb, a1 = bb, a2 = bb, a3 = bb;
            if (w3_bf) {
                const unsigned short* q = (const unsigned short*)W3 + j;
#pragma unroll
                for (int k = 0; k < 16; ++k) {
                    float w = bf2f(q[k * 811]);
                    a0 += h2r[0][k] * w; a1 += h2r[1][k] * w;
                    a2 += h2r[2][k] * w; a3 += h2r[3][k] * w;
                }
            } else {
                const float* q = (const float*)W3 + j;
#pragma unroll
                for (int k = 0; k < 16; ++k) {
                    float w = q[k * 811];
                    a0 += h2r[0][k] * w; a1 += h2r[1][k] * w;
                    a2 += h2r[2][k] * w; a3 += h2r[3][k] * w;
                }
            }
            SH[0 * REG + OFF_W + j] = a0;
            SH[1 * REG + OFF_W + j] = a1;
            SH[2 * REG + OFF_W + j] = a2;
            SH[3 * REG + OFF_W + j] = a3;
        }
    }
    __syncthreads();   // barrier #2: weights ready — conv phase is wave-local

    // ==== per-wave CNN: wave wv owns sample b0+wv ====
    const int sb = wv * REG;

    // ---- conv1 (1->3, 28x28 -> fused pool -> 13x13x3 bf16) ----
    {
        float wc[27], cb[3];
#pragma unroll
        for (int i = 0; i < 27; ++i) wc[i] = SH[sb + OFF_W + i];
#pragma unroll
        for (int c = 0; c < 3; ++c) cb[c] = SH[sb + OFF_W + 27 + c];
        const unsigned* suw = (const unsigned*)&SH[sb];  // 2 pixels per dword
#pragma unroll
        for (int it = 0; it < 3; ++it) {
            int pix = lane + it * 64;
            if (pix < 169) {
                int py = pix / 13, px = pix - py * 13;
                int iy = 2 * py;
                float pt[4][4];
#pragma unroll
                for (int dy = 0; dy < 4; ++dy) {
                    int r = (iy + dy) * 14 + px;
                    unsigned d0 = suw[r], d1 = suw[r + 1];
                    pt[dy][0] = __uint_as_float(d0 << 16);
                    pt[dy][1] = __uint_as_float(d0 & 0xffff0000u);
                    pt[dy][2] = __uint_as_float(d1 << 16);
                    pt[dy][3] = __uint_as_float(d1 & 0xffff0000u);
                }
                unsigned short* op = &su[sb * 2 + HW_P1 + py * 14 + px];
#pragma unroll
                for (int c = 0; c < 3; ++c) {
                    float a00 = 0.f, a01 = 0.f, a10 = 0.f, a11 = 0.f;
#pragma unroll
                    for (int ky = 0; ky < 3; ++ky)
#pragma unroll
                        for (int kx = 0; kx < 3; ++kx) {
                            float w = wc[c * 9 + ky * 3 + kx];
                            a00 += pt[ky][kx] * w;
                            a01 += pt[ky][kx + 1] * w;
                            a10 += pt[ky + 1][kx] * w;
                            a11 += pt[ky + 1][kx + 1] * w;
                        }
                    float m = fmaxf(fmaxf(a00, a01), fmaxf(a10, a11));
                    op[c * 182] = f2bf(fmaxf(m + cb[c], 0.f));
                }
            }
        }
    }
    wsync();

    // ---- conv2 (3->6, 13x13 -> fused pool -> 5x5x6 fp32), ci-outer ----
    // ci-outer keeps live set ~35 regs (12 acc + 16 patch) vs 80 in the
    // hoisted form — stays well under the spill cliff.
    {
        int g = lane >> 5, q = lane & 31;
        if (q < 25) {
            int py = q / 5, px = q - py * 5;
            const unsigned* p1w = (const unsigned*)&SH[sb + 1204];  // P1 dwords
            float acc[3][4];
#pragma unroll
            for (int it = 0; it < 3; ++it)
#pragma unroll
                for (int i = 0; i < 4; ++i) acc[it][i] = 0.f;
#pragma unroll
            for (int ci = 0; ci < 3; ++ci) {
                float pt[4][4];
#pragma unroll
                for (int dy = 0; dy < 4; ++dy) {
                    int r = ci * 91 + (2 * py + dy) * 7 + px;
                    unsigned d0 = p1w[r], d1 = p1w[r + 1];
                    pt[dy][0] = __uint_as_float(d0 << 16);
                    pt[dy][1] = __uint_as_float(d0 & 0xffff0000u);
                    pt[dy][2] = __uint_as_float(d1 << 16);
                    pt[dy][3] = __uint_as_float(d1 & 0xffff0000u);
                }
#pragma unroll
                for (int it = 0; it < 3; ++it) {
                    int c = it * 2 + g;
                    const int wo = sb + OFF_W + 30 + c * 27 + ci;
#pragma unroll
                    for (int ky = 0; ky < 3; ++ky)
#pragma unroll
                        for (int kx = 0; kx < 3; ++kx) {
                            float w = SH[wo + (ky * 3 + kx) * 3];
                            acc[it][0] += pt[ky][kx] * w;
                            acc[it][1] += pt[ky][kx + 1] * w;
                            acc[it][2] += pt[ky + 1][kx] * w;
                            acc[it][3] += pt[ky + 1][kx + 1] * w;
                        }
                }
            }
#pragma unroll
            for (int it = 0; it < 3; ++it) {
                int c = it * 2 + g;
                float m = fmaxf(fmaxf(acc[it][0], acc[it][1]),
                                fmaxf(acc[it][2], acc[it][3]));
                SH[sb + OFF_P2 + c * 25 + q] = fmaxf(m + SH[sb + OFF_W + 192 + c], 0.f);
            }
        }
    }
    wsync();

    // ---- conv3 (6->3, 5x5 -> 3x3) + relu, 54-lane split over ci halves ----
    {
        float acc = 0.f;
        int pq = lane % 27;            // 0..26: c*9 + pos
        int half = lane / 27;          // 0,1 active; lane>=54 idle
        int c = pq / 9, pos = pq - c * 9;
        int py = pos / 3, px = pos - py * 3;
        if (lane < 54) {
            const int wo = sb + OFF_W + 198 + c * 54;
            const int cb3 = half * 3;
#pragma unroll
            for (int ky = 0; ky < 3; ++ky)
#pragma unroll
                for (int kx = 0; kx < 3; ++kx)
#pragma unroll
                    for (int ci = 0; ci < 3; ++ci)
                        acc += SH[sb + OFF_P2 + (cb3 + ci) * 25 + (py + ky) * 5 + px + kx] *
                               SH[wo + (ky * 3 + kx) * 6 + cb3 + ci];
        }
        float other = __shfl(acc, (lane + 27) & 63);
        if (lane < 27)
            SH[sb + OFF_P3 + pq] = fmaxf(acc + other + SH[sb + OFF_W + 360 + c], 0.f);
    }
    wsync();

    // ---- conv4 (3->16) + bias + residual -> out, 32-lane split over pp ----
    // P3 channel-major (ci*9+pp), w4 spatial-major (pp*3+ci).
    {
        float acc = 0.f;
        int os = lane & 15, h = (lane >> 4) & 1;
        if (lane < 32) {
            const int wo = sb + OFF_W + 363 + os * 27;
            int p0 = h ? 4 : 0, p1 = h ? 9 : 4;
            for (int pp = p0; pp < p1; ++pp)
#pragma unroll
                for (int ci = 0; ci < 3; ++ci)
                    acc += SH[sb + OFF_P3 + ci * 9 + pp] * SH[wo + pp * 3 + ci];
        }
        float other = __shfl(acc, (lane + 16) & 63);
        if (lane < 16) {
            float tot = acc + other + SH[sb + OFF_W + 795 + os] + s_st[wv][os];
            int gi = (b0 + wv) * 16 + os;
            if (out_bf) ((unsigned short*)out)[gi] = f2bf(tot);
            else        ((float*)out)[gi] = tot;
        }
    }
}

extern "C" void kernel_launch(void* const* d_in, const int* in_sizes, int n_in,
                              void* d_out, int out_size, void* d_ws, size_t ws_size,
                              hipStream_t stream) {
    (void)d_ws; (void)ws_size; (void)n_in; (void)out_size;
    int B = in_sizes[1] / 16;              // 16384
    int nblocks = B / NSAMP;               // 4096
    int nswz = (nblocks % 8 == 0) ? (nblocks / 8) : 0;

    dyncnn4_kernel<<<nblocks, BLK, 0, stream>>>(
        d_in[0], d_in[1], d_in[2], d_in[3], d_in[4], d_in[5], d_in[6], d_in[7],
        d_out, B, nswz);
}